// Round 3
// baseline (23165.622 us; speedup 1.0000x reference)
//
#include <hip/hip_runtime.h>
#include <cstdint>
#include <cstddef>

#define Bc 8
#define Lc 2048
#define Dc 1152
#define STRIDE 2080
#define G 8

// ---- K1 GEMM geometry ----
#define T_BLK 128            // positions per block
#define KT 32                // K-tile
#define NKS (Dc / KT)        // 36 k-steps
#define NCHUNK 6             // e-chunks (grid.y)
#define ECH 192              // e's per chunk
#define NEIT 3               // e-iters of 64 within a chunk
// LDS float offsets: Hs[129 rows][8 slots][4] | Wq[64][8][4] | Wk[64][8][4]
#define HS_NU 1032           // 129*8 16B-units
#define W_NU 512             // 64*8
#define QS_F 4128
#define KS_F 6176

__device__ __forceinline__ void gld16(const float* g, float* l) {
    __builtin_amdgcn_global_load_lds(
        (const __attribute__((address_space(1))) void*)(g),
        (__attribute__((address_space(3))) void*)(l), 16, 0, 0);
}

// ---------------- Kernel 1: tiled fp32 GEMM + fused cos-stats ----------------
// Stats for position t: q = Wq.h[t-1], k = Wk.h[t]; accumulate qq,kk,qk over e.
// Block: 128 positions x 192 e's (both Wq and Wk), full K. Thread (tx,ty):
// 8 t-rows {ty+16i}, 4 e-cols {tx+16j}. H window rows t0-1..t0+127 staged per
// k-step with XOR-swizzled slots (^(row&3)); W tiles swizzled ^(e&7). All
// ds_read_b128 bank-conflict-free; staging via global_load_lds w=16 with
// pre-swizzled global source (LDS dest stays linear).
__global__ __launch_bounds__(256, 3) void k1_gemm(
    const float* __restrict__ H, const float* __restrict__ Wq,
    const float* __restrict__ Wk, float* __restrict__ partial)
{
    __shared__ __align__(16) float Lds[8224];   // 32896 B
    float* Hs = Lds;
    float* Qs = Lds + QS_F;
    float* Ks = Lds + KS_F;

    const int tid = threadIdx.x;
    const int bx = blockIdx.x;          // batch*16 + tb
    const int chunk = blockIdx.y;       // 0..5
    const int batch = bx >> 4;
    const int tb = bx & 15;
    const int t0 = 1 + tb * T_BLK;
    const float* Hb = H + (size_t)batch * Lc * Dc;
    const int e0 = chunk * ECH;

    const int tx = tid & 15;
    const int ty = tid >> 4;

    float qq[8], kk[8], qk[8];
    #pragma unroll
    for (int i = 0; i < 8; ++i) { qq[i] = 0.f; kk[i] = 0.f; qk[i] = 0.f; }

    for (int eit = 0; eit < NEIT; ++eit) {
        float qacc[8][4], kacc[8][4];
        #pragma unroll
        for (int i = 0; i < 8; ++i)
            #pragma unroll
            for (int j = 0; j < 4; ++j) { qacc[i][j] = 0.f; kacc[i][j] = 0.f; }
        const int eb = e0 + eit * 64;

        for (int ks = 0; ks < NKS; ++ks) {
            const int kb = ks * KT;
            // stage H window (129 rows x 128 B), source slot pre-swizzled
            for (int u = tid; u < HS_NU; u += 256) {
                int row = u >> 3;
                int sl = (u & 7) ^ (row & 3);
                int grow = t0 - 1 + row; if (grow > Lc - 1) grow = Lc - 1;
                gld16(Hb + (size_t)grow * Dc + kb + sl * 4, Hs + u * 4);
            }
            // stage Wq/Wk tiles (64 rows x 128 B each)
            for (int u = tid; u < W_NU; u += 256) {
                int er = u >> 3;
                int sl = (u & 7) ^ (er & 7);
                size_t off = (size_t)(eb + er) * Dc + kb + sl * 4;
                gld16(Wq + off, Qs + u * 4);
                gld16(Wk + off, Ks + u * 4);
            }
            asm volatile("s_waitcnt vmcnt(0)" ::: "memory");
            __syncthreads();

            #pragma unroll
            for (int g = 0; g < 8; ++g) {
                float4 wqf[4], wkf[4];
                #pragma unroll
                for (int j = 0; j < 4; ++j) {
                    int e = tx + 16 * j;
                    int so = e * 32 + ((g ^ (e & 7)) * 4);
                    wqf[j] = *(const float4*)(Qs + so);
                    wkf[j] = *(const float4*)(Ks + so);
                }
                #pragma unroll
                for (int i = 0; i < 8; ++i) {
                    int rq = ty + 16 * i;
                    int rk = rq + 1;
                    float4 hq = *(const float4*)(Hs + rq * 32 + ((g ^ (rq & 3)) * 4));
                    float4 hk = *(const float4*)(Hs + rk * 32 + ((g ^ (rk & 3)) * 4));
                    #pragma unroll
                    for (int j = 0; j < 4; ++j) {
                        qacc[i][j] += hq.x*wqf[j].x + hq.y*wqf[j].y + hq.z*wqf[j].z + hq.w*wqf[j].w;
                        kacc[i][j] += hk.x*wkf[j].x + hk.y*wkf[j].y + hk.z*wkf[j].z + hk.w*wkf[j].w;
                    }
                }
            }
            __syncthreads();
        }
        // fold this e-iter's q/k into running stats
        #pragma unroll
        for (int i = 0; i < 8; ++i)
            #pragma unroll
            for (int j = 0; j < 4; ++j) {
                qq[i] += qacc[i][j] * qacc[i][j];
                kk[i] += kacc[i][j] * kacc[i][j];
                qk[i] += qacc[i][j] * kacc[i][j];
            }
    }

    // reduce across the 16 tx-lanes (xor 1,2,4,8 stays within the 16-group)
    #pragma unroll
    for (int i = 0; i < 8; ++i) {
        #pragma unroll
        for (int off = 1; off <= 8; off <<= 1) {
            qq[i] += __shfl_xor(qq[i], off, 64);
            kk[i] += __shfl_xor(kk[i], off, 64);
            qk[i] += __shfl_xor(qk[i], off, 64);
        }
    }
    if (tx == 0) {
        #pragma unroll
        for (int i = 0; i < 8; ++i) {
            int t = t0 + ty + 16 * i;
            if (t < Lc) {
                size_t idx = (((size_t)chunk * Bc + batch) * Lc + t) * 3;
                partial[idx + 0] = qq[i];
                partial[idx + 1] = kk[i];
                partial[idx + 2] = qk[i];
            }
        }
    }
}

// ---------------- Kernel 1b: deterministic chunk-reduce -> bl ----------------
__global__ __launch_bounds__(256) void k1b_reduce(
    const float* __restrict__ partial, const float* __restrict__ ltemp,
    const float* __restrict__ bbias, float* __restrict__ bl_out)
{
    int idx = blockIdx.x * 256 + threadIdx.x;   // batch*Lc + t
    if (idx >= Bc * Lc) return;
    int t = idx & (Lc - 1);
    if (t == 0) return;
    float qq = 0.f, kk = 0.f, qk = 0.f;
    #pragma unroll
    for (int c = 0; c < NCHUNK; ++c) {
        size_t p = ((size_t)c * Bc * Lc + idx) * 3;
        qq += partial[p];
        kk += partial[p + 1];
        qk += partial[p + 2];
    }
    float T = expf(ltemp[0]);
    T = fminf(fmaxf(T, 0.1f), 10.0f);
    float den = fmaxf(sqrtf(qq), 1e-12f) * fmaxf(sqrtf(kk), 1e-12f);
    bl_out[idx] = (1.0f - qk / den) * T + bbias[0];
}

// ---------------- Kernel 2: boundary decision + stable compaction ----------------
__global__ __launch_bounds__(256) void k2_boundary(
    const float* __restrict__ bl_in, const int* __restrict__ mask,
    float* __restrict__ pv, int* __restrict__ bpos, int* __restrict__ nb)
{
    int b = blockIdx.x;
    int tid = threadIdx.x;
    const float* blb = bl_in + b * Lc;
    const int* mb = mask + b * Lc;

    float blv[8]; int f[8];
    int t0 = tid * 8;
    int s = 0;
    #pragma unroll
    for (int i = 0; i < 8; ++i) {
        int t = t0 + i;
        float v = (t == 0) ? 10.0f : blb[t];
        blv[i] = v;
        f[i] = (v > 0.0f && mb[t] != 0) ? 1 : 0;
        s += f[i];
    }
    int lane = tid & 63, wv = tid >> 6;
    int sc = s;
    #pragma unroll
    for (int off = 1; off < 64; off <<= 1) {
        int o = __shfl_up(sc, off, 64);
        if (lane >= off) sc += o;
    }
    __shared__ int wsums[4];
    if (lane == 63) wsums[wv] = sc;
    __syncthreads();
    int woff = 0;
    #pragma unroll
    for (int w = 0; w < 4; ++w) woff += (w < wv) ? wsums[w] : 0;
    int excl = woff + sc - s;
    int total = wsums[0] + wsums[1] + wsums[2] + wsums[3];

    float* pvb = pv + b * STRIDE;
    int* bpb = bpos + b * STRIDE;
    int r = excl;
    #pragma unroll
    for (int i = 0; i < 8; ++i) {
        if (f[i]) {
            int t = t0 + i;
            float p;
            if (t == 0) {
                p = 1.0f;
            } else {
                p = 1.0f / (1.0f + expf(-2.0f * blv[i]));
                p = fminf(fmaxf(p, 1e-4f), 1.0f - 1e-4f);
            }
            bpb[r] = t;
            pvb[r] = p;
            r += 1;
        }
    }
    if (tid == 0) nb[b] = total;
    for (int j = total + tid; j < STRIDE; j += 256) { bpb[j] = Lc; pvb[j] = 0.0f; }
}

// ---------------- Kernel 3: EMA over boundary tokens + span expansion ----------------
__global__ __launch_bounds__(128) void k3_ema(
    const float* __restrict__ H, const float* __restrict__ pv,
    const int* __restrict__ bpos, const int* __restrict__ nb,
    float* __restrict__ out)
{
    int b = blockIdx.x;
    int ch = blockIdx.y * 128 + threadIdx.x;
    const float* Hb = H + (size_t)b * Lc * Dc + ch;
    float* Ob = out + (size_t)b * Lc * Dc + ch;
    const float* pvb = pv + b * STRIDE;
    const int* bpb = bpos + b * STRIDE;
    int n = nb[b];
    int ng = (n + G - 1) / G;

    float xA[G], pA[G]; int tA[G + 1];
    #pragma unroll
    for (int i = 0; i < G; ++i) {
        int t = bpb[i];
        tA[i] = t;
        pA[i] = pvb[i];
        xA[i] = (t < Lc) ? Hb[(size_t)t * Dc] : 0.0f;
    }
    tA[G] = bpb[G];

    float h = 0.0f;
    for (int g = 0; g < ng; ++g) {
        int nbase = (g + 1) * G;
        float xB[G], pB[G]; int tB[G + 1];
        #pragma unroll
        for (int i = 0; i < G; ++i) {
            int t = bpb[nbase + i];
            tB[i] = t;
            pB[i] = pvb[nbase + i];
            xB[i] = (t < Lc) ? Hb[(size_t)t * Dc] : 0.0f;
        }
        tB[G] = bpb[nbase + G];
        #pragma unroll
        for (int i = 0; i < G; ++i) {
            h = (1.0f - pA[i]) * h + pA[i] * xA[i];
            int te = tA[i + 1];
            for (int tt = tA[i]; tt < te; ++tt) Ob[(size_t)tt * Dc] = h;
        }
        #pragma unroll
        for (int i = 0; i < G; ++i) { xA[i] = xB[i]; pA[i] = pB[i]; tA[i] = tB[i]; }
        tA[G] = tB[G];
    }
}

extern "C" void kernel_launch(void* const* d_in, const int* in_sizes, int n_in,
                              void* d_out, int out_size, void* d_ws, size_t ws_size,
                              hipStream_t stream)
{
    const float* H  = (const float*)d_in[0];
    const float* Wq = (const float*)d_in[1];
    const float* Wk = (const float*)d_in[2];
    const float* lt = (const float*)d_in[3];
    const float* bb = (const float*)d_in[4];
    const int* mask = (const int*)d_in[5];
    float* out = (float*)d_out;

    char* ws = (char*)d_ws;
    float* bl   = (float*)ws;                                     // 8*2048 floats
    float* pv   = (float*)(ws + (size_t)Bc * Lc * 4);
    int*   bpos = (int*)  (ws + (size_t)Bc * Lc * 4 + (size_t)Bc * STRIDE * 4);
    int*   nbp  = (int*)  (ws + (size_t)Bc * Lc * 4 + 2ull * Bc * STRIDE * 4);
    // chunk partials (6 x 16384 x 3 fp32 = 1.18 MB) live in d_out's head;
    // K3 fully overwrites d_out afterwards.
    float* partial = out;

    hipLaunchKernelGGL(k1_gemm, dim3(Bc * 16, NCHUNK), dim3(256), 0, stream,
                       H, Wq, Wk, partial);
    hipLaunchKernelGGL(k1b_reduce, dim3((Bc * Lc + 255) / 256), dim3(256), 0, stream,
                       partial, lt, bb, bl);
    hipLaunchKernelGGL(k2_boundary, dim3(Bc), dim3(256), 0, stream,
                       bl, mask, pv, bpos, nbp);
    hipLaunchKernelGGL(k3_ema, dim3(Bc, 9), dim3(128), 0, stream,
                       H, pv, bpos, nbp, out);
}

// Round 4
// 1613.108 us; speedup vs baseline: 14.3609x; 14.3609x over previous
//
#include <hip/hip_runtime.h>
#include <cstdint>
#include <cstddef>

#define Bc 8
#define Lc 2048
#define Dc 1152
#define STRIDE 2080
#define G 8

// ---- K1 GEMM geometry ----
#define T_BLK 128            // positions per block
#define KT 32                // K-tile
#define NKS (Dc / KT)        // 36 k-steps
#define NCHUNK 6             // e-chunks (grid.y)
#define ECH 192              // e's per chunk
#define NEIT 3               // e-iters of 64 within a chunk
// LDS float offsets: Hs[129 rows][8 slots][4] | Wq[64][8][4] | Wk[64][8][4]
#define HS_NU 1032           // 129*8 16B-units
#define W_NU 512             // 64*8
#define QS_F 4128
#define KS_F 6176

__device__ __forceinline__ void gld16(const float* g, float* l) {
    __builtin_amdgcn_global_load_lds(
        (const __attribute__((address_space(1))) void*)(g),
        (__attribute__((address_space(3))) void*)(l), 16, 0, 0);
}

#define DOT4(a, b) ((a).x*(b).x + (a).y*(b).y + (a).z*(b).z + (a).w*(b).w)

// ---------------- Kernel 1: tiled fp32 GEMM + fused cos-stats ----------------
// Stats for position t: q = Wq.h[t-1], k = Wk.h[t]; accumulate qq,kk,qk over e.
// Block: 128 positions x 192 e's. Thread (tx,ty): 8 t-rows {ty+16i}, 4 e-cols
// {tx+16j}. Accumulators are NAMED float4 SSA values (qa0..qa7 / ka0..ka7,
// component = e-col) so they can never fall to scratch (round-3 lesson:
// array allocas went to local memory -> 49 GB scratch traffic).
// LDS 16B slots XOR-swizzled ^(row&7); staged via global_load_lds w=16 with
// pre-swizzled global source (LDS dest linear per-wave).
__global__ __launch_bounds__(256, 2) void k1_gemm(
    const float* __restrict__ H, const float* __restrict__ Wq,
    const float* __restrict__ Wk, float* __restrict__ partial)
{
    __shared__ __align__(16) float Lds[8224];   // 32896 B
    float* Hs = Lds;
    float* Qs = Lds + QS_F;
    float* Ks = Lds + KS_F;

    const int tid = threadIdx.x;
    const int bx = blockIdx.x;          // batch*16 + tb
    const int chunk = blockIdx.y;       // 0..5
    const int batch = bx >> 4;
    const int tb = bx & 15;
    const int t0 = 1 + tb * T_BLK;
    const float* Hb = H + (size_t)batch * Lc * Dc;
    const int e0 = chunk * ECH;

    const int tx = tid & 15;
    const int ty = tid >> 4;

    float qq[8], kk[8], qk[8];
    #pragma unroll
    for (int i = 0; i < 8; ++i) { qq[i] = 0.f; kk[i] = 0.f; qk[i] = 0.f; }

    for (int eit = 0; eit < NEIT; ++eit) {
        const int eb = e0 + eit * 64;
        float4 qa0{0,0,0,0}, qa1{0,0,0,0}, qa2{0,0,0,0}, qa3{0,0,0,0};
        float4 qa4{0,0,0,0}, qa5{0,0,0,0}, qa6{0,0,0,0}, qa7{0,0,0,0};
        float4 ka0{0,0,0,0}, ka1{0,0,0,0}, ka2{0,0,0,0}, ka3{0,0,0,0};
        float4 ka4{0,0,0,0}, ka5{0,0,0,0}, ka6{0,0,0,0}, ka7{0,0,0,0};

        for (int ks = 0; ks < NKS; ++ks) {
            const int kb = ks * KT;
            // stage H window (129 rows x 128 B), source slot pre-swizzled
            for (int u = tid; u < HS_NU; u += 256) {
                int row = u >> 3;
                int sl = (u & 7) ^ (row & 7);
                int grow = t0 - 1 + row; if (grow > Lc - 1) grow = Lc - 1;
                gld16(Hb + (size_t)grow * Dc + kb + sl * 4, Hs + u * 4);
            }
            // stage Wq/Wk tiles (64 rows x 128 B each)
            for (int u = tid; u < W_NU; u += 256) {
                int er = u >> 3;
                int sl = (u & 7) ^ (er & 7);
                size_t off = (size_t)(eb + er) * Dc + kb + sl * 4;
                gld16(Wq + off, Qs + u * 4);
                gld16(Wk + off, Ks + u * 4);
            }
            __syncthreads();   // drains vmcnt (compiler emits full waitcnt before s_barrier)

            for (int g = 0; g < 8; ++g) {
                float4 wq0, wq1, wq2, wq3, wk0, wk1, wk2, wk3;
                {
                    int e0l = tx;
                    int e1l = tx + 16, e2l = tx + 32, e3l = tx + 48;
                    wq0 = *(const float4*)(Qs + e0l * 32 + ((g ^ (e0l & 7)) << 2));
                    wq1 = *(const float4*)(Qs + e1l * 32 + ((g ^ (e1l & 7)) << 2));
                    wq2 = *(const float4*)(Qs + e2l * 32 + ((g ^ (e2l & 7)) << 2));
                    wq3 = *(const float4*)(Qs + e3l * 32 + ((g ^ (e3l & 7)) << 2));
                    wk0 = *(const float4*)(Ks + e0l * 32 + ((g ^ (e0l & 7)) << 2));
                    wk1 = *(const float4*)(Ks + e1l * 32 + ((g ^ (e1l & 7)) << 2));
                    wk2 = *(const float4*)(Ks + e2l * 32 + ((g ^ (e2l & 7)) << 2));
                    wk3 = *(const float4*)(Ks + e3l * 32 + ((g ^ (e3l & 7)) << 2));
                }
                #define ROWSTEP(i)                                                        \
                {                                                                         \
                    int rq = ty + 16 * (i);                                               \
                    int rk = rq + 1;                                                      \
                    float4 hq = *(const float4*)(Hs + rq * 32 + ((g ^ (rq & 7)) << 2));   \
                    float4 hk = *(const float4*)(Hs + rk * 32 + ((g ^ (rk & 7)) << 2));   \
                    qa##i.x += DOT4(hq, wq0); qa##i.y += DOT4(hq, wq1);                   \
                    qa##i.z += DOT4(hq, wq2); qa##i.w += DOT4(hq, wq3);                   \
                    ka##i.x += DOT4(hk, wk0); ka##i.y += DOT4(hk, wk1);                   \
                    ka##i.z += DOT4(hk, wk2); ka##i.w += DOT4(hk, wk3);                   \
                }
                ROWSTEP(0) ROWSTEP(1) ROWSTEP(2) ROWSTEP(3)
                ROWSTEP(4) ROWSTEP(5) ROWSTEP(6) ROWSTEP(7)
                #undef ROWSTEP
            }
            __syncthreads();
        }
        // fold this e-iter's q/k into running stats
        #define FOLD(i)                                                                   \
        {                                                                                 \
            qq[i] += qa##i.x*qa##i.x + qa##i.y*qa##i.y + qa##i.z*qa##i.z + qa##i.w*qa##i.w; \
            kk[i] += ka##i.x*ka##i.x + ka##i.y*ka##i.y + ka##i.z*ka##i.z + ka##i.w*ka##i.w; \
            qk[i] += qa##i.x*ka##i.x + qa##i.y*ka##i.y + qa##i.z*ka##i.z + qa##i.w*ka##i.w; \
        }
        FOLD(0) FOLD(1) FOLD(2) FOLD(3) FOLD(4) FOLD(5) FOLD(6) FOLD(7)
        #undef FOLD
    }

    // reduce across the 16 tx-lanes (xor 1,2,4,8 stays within the 16-group)
    #pragma unroll
    for (int i = 0; i < 8; ++i) {
        #pragma unroll
        for (int off = 1; off <= 8; off <<= 1) {
            qq[i] += __shfl_xor(qq[i], off, 64);
            kk[i] += __shfl_xor(kk[i], off, 64);
            qk[i] += __shfl_xor(qk[i], off, 64);
        }
    }
    if (tx == 0) {
        #pragma unroll
        for (int i = 0; i < 8; ++i) {
            int t = t0 + ty + 16 * i;
            if (t < Lc) {
                size_t idx = (((size_t)chunk * Bc + batch) * Lc + t) * 3;
                partial[idx + 0] = qq[i];
                partial[idx + 1] = kk[i];
                partial[idx + 2] = qk[i];
            }
        }
    }
}

// ---------------- Kernel 1b: deterministic chunk-reduce -> bl ----------------
__global__ __launch_bounds__(256) void k1b_reduce(
    const float* __restrict__ partial, const float* __restrict__ ltemp,
    const float* __restrict__ bbias, float* __restrict__ bl_out)
{
    int idx = blockIdx.x * 256 + threadIdx.x;   // batch*Lc + t
    if (idx >= Bc * Lc) return;
    int t = idx & (Lc - 1);
    if (t == 0) return;
    float qq = 0.f, kk = 0.f, qk = 0.f;
    #pragma unroll
    for (int c = 0; c < NCHUNK; ++c) {
        size_t p = ((size_t)c * Bc * Lc + idx) * 3;
        qq += partial[p];
        kk += partial[p + 1];
        qk += partial[p + 2];
    }
    float T = expf(ltemp[0]);
    T = fminf(fmaxf(T, 0.1f), 10.0f);
    float den = fmaxf(sqrtf(qq), 1e-12f) * fmaxf(sqrtf(kk), 1e-12f);
    bl_out[idx] = (1.0f - qk / den) * T + bbias[0];
}

// ---------------- Kernel 2: boundary decision + stable compaction ----------------
__global__ __launch_bounds__(256) void k2_boundary(
    const float* __restrict__ bl_in, const int* __restrict__ mask,
    float* __restrict__ pv, int* __restrict__ bpos, int* __restrict__ nb)
{
    int b = blockIdx.x;
    int tid = threadIdx.x;
    const float* blb = bl_in + b * Lc;
    const int* mb = mask + b * Lc;

    float blv[8]; int f[8];
    int t0 = tid * 8;
    int s = 0;
    #pragma unroll
    for (int i = 0; i < 8; ++i) {
        int t = t0 + i;
        float v = (t == 0) ? 10.0f : blb[t];
        blv[i] = v;
        f[i] = (v > 0.0f && mb[t] != 0) ? 1 : 0;
        s += f[i];
    }
    int lane = tid & 63, wv = tid >> 6;
    int sc = s;
    #pragma unroll
    for (int off = 1; off < 64; off <<= 1) {
        int o = __shfl_up(sc, off, 64);
        if (lane >= off) sc += o;
    }
    __shared__ int wsums[4];
    if (lane == 63) wsums[wv] = sc;
    __syncthreads();
    int woff = 0;
    #pragma unroll
    for (int w = 0; w < 4; ++w) woff += (w < wv) ? wsums[w] : 0;
    int excl = woff + sc - s;
    int total = wsums[0] + wsums[1] + wsums[2] + wsums[3];

    float* pvb = pv + b * STRIDE;
    int* bpb = bpos + b * STRIDE;
    int r = excl;
    #pragma unroll
    for (int i = 0; i < 8; ++i) {
        if (f[i]) {
            int t = t0 + i;
            float p;
            if (t == 0) {
                p = 1.0f;
            } else {
                p = 1.0f / (1.0f + expf(-2.0f * blv[i]));
                p = fminf(fmaxf(p, 1e-4f), 1.0f - 1e-4f);
            }
            bpb[r] = t;
            pvb[r] = p;
            r += 1;
        }
    }
    if (tid == 0) nb[b] = total;
    for (int j = total + tid; j < STRIDE; j += 256) { bpb[j] = Lc; pvb[j] = 0.0f; }
}

// ---------------- Kernel 3: EMA over boundary tokens + span expansion ----------------
__global__ __launch_bounds__(128) void k3_ema(
    const float* __restrict__ H, const float* __restrict__ pv,
    const int* __restrict__ bpos, const int* __restrict__ nb,
    float* __restrict__ out)
{
    int b = blockIdx.x;
    int ch = blockIdx.y * 128 + threadIdx.x;
    const float* Hb = H + (size_t)b * Lc * Dc + ch;
    float* Ob = out + (size_t)b * Lc * Dc + ch;
    const float* pvb = pv + b * STRIDE;
    const int* bpb = bpos + b * STRIDE;
    int n = nb[b];
    int ng = (n + G - 1) / G;

    float xA[G], pA[G]; int tA[G + 1];
    #pragma unroll
    for (int i = 0; i < G; ++i) {
        int t = bpb[i];
        tA[i] = t;
        pA[i] = pvb[i];
        xA[i] = (t < Lc) ? Hb[(size_t)t * Dc] : 0.0f;
    }
    tA[G] = bpb[G];

    float h = 0.0f;
    for (int g = 0; g < ng; ++g) {
        int nbase = (g + 1) * G;
        float xB[G], pB[G]; int tB[G + 1];
        #pragma unroll
        for (int i = 0; i < G; ++i) {
            int t = bpb[nbase + i];
            tB[i] = t;
            pB[i] = pvb[nbase + i];
            xB[i] = (t < Lc) ? Hb[(size_t)t * Dc] : 0.0f;
        }
        tB[G] = bpb[nbase + G];
        #pragma unroll
        for (int i = 0; i < G; ++i) {
            h = (1.0f - pA[i]) * h + pA[i] * xA[i];
            int te = tA[i + 1];
            for (int tt = tA[i]; tt < te; ++tt) Ob[(size_t)tt * Dc] = h;
        }
        #pragma unroll
        for (int i = 0; i < G; ++i) { xA[i] = xB[i]; pA[i] = pB[i]; tA[i] = tB[i]; }
        tA[G] = tB[G];
    }
}

extern "C" void kernel_launch(void* const* d_in, const int* in_sizes, int n_in,
                              void* d_out, int out_size, void* d_ws, size_t ws_size,
                              hipStream_t stream)
{
    const float* H  = (const float*)d_in[0];
    const float* Wq = (const float*)d_in[1];
    const float* Wk = (const float*)d_in[2];
    const float* lt = (const float*)d_in[3];
    const float* bb = (const float*)d_in[4];
    const int* mask = (const int*)d_in[5];
    float* out = (float*)d_out;

    char* ws = (char*)d_ws;
    float* bl   = (float*)ws;                                     // 8*2048 floats
    float* pv   = (float*)(ws + (size_t)Bc * Lc * 4);
    int*   bpos = (int*)  (ws + (size_t)Bc * Lc * 4 + (size_t)Bc * STRIDE * 4);
    int*   nbp  = (int*)  (ws + (size_t)Bc * Lc * 4 + 2ull * Bc * STRIDE * 4);
    // chunk partials (6 x 16384 x 3 fp32 = 1.18 MB) live in d_out's head;
    // K3 fully overwrites d_out afterwards.
    float* partial = out;

    hipLaunchKernelGGL(k1_gemm, dim3(Bc * 16, NCHUNK), dim3(256), 0, stream,
                       H, Wq, Wk, partial);
    hipLaunchKernelGGL(k1b_reduce, dim3((Bc * Lc + 255) / 256), dim3(256), 0, stream,
                       partial, lt, bb, bl);
    hipLaunchKernelGGL(k2_boundary, dim3(Bc), dim3(256), 0, stream,
                       bl, mask, pv, bpos, nbp);
    hipLaunchKernelGGL(k3_ema, dim3(Bc, 9), dim3(128), 0, stream,
                       H, pv, bpos, nbp, out);
}